// Round 1
// baseline (730.683 us; speedup 1.0000x reference)
//
#include <hip/hip_runtime.h>
#include <hip/hip_bf16.h>

// FeatureAlign: deformable 3x3 conv, G=4 offset groups, PAD=1.
//   x:        (8, 256, 64, 64) fp32
//   shape:    (8,   4, 64, 64) fp32
//   w_offset: (72, 4)          fp32   (72 = G*2*K = 4*2*9)
//   w_deform: (256, 256, 3, 3) fp32
//   out:      (8, 256, 64, 64) fp32, ReLU
//
// offset[b,o,h,w] = sum_c w_offset[o,c]*shape[b,c,h,w]; o = ((g*9+k)*2 + {dy,dx})
// py = h + ky-1 + dy; px = w + kx-1 + dx; bilinear sample with zero pad.
// out[b,o,h,w] = relu( sum_{g,c,k} w_deform[o, g*64+c, ky, kx] * sampled )

#define Bn   8
#define CIN  256
#define COUT 256
#define Hn   64
#define Wn   64
#define Gn   4
#define Kn   9
#define CPG  64           // channels per offset group
#define GK   (Gn*Kn)      // 36

// ---------------------------------------------------------------------------
// Prep: transpose w_deform (o,g,c,k) -> wT[gk][c][o]  (coalesced writes)
// ---------------------------------------------------------------------------
__global__ void fa_wtrans(const float* __restrict__ w, float* __restrict__ wT) {
    int i = blockIdx.x * 256 + threadIdx.x;          // over 36*64*256 = 589824
    if (i >= GK * CPG * COUT) return;
    int o  = i & 255;
    int c  = (i >> 8) & 63;
    int gk = i >> 14;
    int g  = gk / Kn, k = gk - g * Kn;
    wT[i] = w[((o * Gn + g) * CPG + c) * Kn + k];
}

// ---------------------------------------------------------------------------
// Main: one block per (b, h). 256 threads.
//   meta phase : all 36 (g,k) x 64 w offset corners/fractions -> LDS
//   per (g,k)  : stage sampled tile s[c=64][w=64] in LDS (bilinear gather),
//                then 8o x 8w register-blocked FMA outer product.
// ---------------------------------------------------------------------------
__global__ __launch_bounds__(256, 2)
void fa_main(const float* __restrict__ x, const float* __restrict__ shp,
             const float* __restrict__ w_off, const float* __restrict__ wT,
             float* __restrict__ out) {
    const int blk = blockIdx.x;            // b*64 + h
    const int b = blk >> 6, h = blk & 63;
    const int t = threadIdx.x;
    const int tcol = t & 31, trow = t >> 5;   // o = i*32+tcol, w = trow*8+j

    __shared__ float s_fy[GK][Wn];
    __shared__ float s_fx[GK][Wn];
    __shared__ int   s_iy[GK][Wn];
    __shared__ int   s_ix[GK][Wn];
    __shared__ __align__(16) float s_tile[CPG][Wn];   // [c][w]

    // ---- meta: 36*64 = 2304 entries, 9 per thread ----
    for (int i = t; i < GK * Wn; i += 256) {
        int gk = i >> 6, w = i & 63;
        int g = gk / Kn, k = gk - g * Kn;
        int ky = k / 3, kx = k - ky * 3;
        int oy = (g * Kn + k) * 2;          // dy channel; dx = oy+1
        float dy = 0.f, dx = 0.f;
#pragma unroll
        for (int c = 0; c < 4; c++) {
            float sv = shp[((b * 4 + c) * Hn + h) * Wn + w];
            dy = fmaf(w_off[(oy    ) * 4 + c], sv, dy);
            dx = fmaf(w_off[(oy + 1) * 4 + c], sv, dx);
        }
        float py = (float)(h + ky - 1) + dy;
        float px = (float)(w + kx - 1) + dx;
        float y0 = floorf(py), x0 = floorf(px);
        s_fy[gk][w] = py - y0;
        s_fx[gk][w] = px - x0;
        s_iy[gk][w] = (int)y0;
        s_ix[gk][w] = (int)x0;
    }

    float acc[8][8];
#pragma unroll
    for (int i = 0; i < 8; i++)
#pragma unroll
        for (int j = 0; j < 8; j++) acc[i][j] = 0.f;

    __syncthreads();

    for (int gk = 0; gk < GK; gk++) {
        int g = gk / Kn;
        const float* xb = x + ((size_t)(b * CIN + g * CPG)) * (Hn * Wn);

        // ---- stage sampled tile: 4096 entries, 16 per thread ----
        for (int i = t; i < CPG * Wn; i += 256) {
            int c = i >> 6, w = i & 63;
            int   iy = s_iy[gk][w], ix = s_ix[gk][w];
            float fy = s_fy[gk][w], fx = s_fx[gk][w];
            const float* xc = xb + c * (Hn * Wn);
            bool y0v = (unsigned)iy       < (unsigned)Hn;
            bool y1v = (unsigned)(iy + 1) < (unsigned)Hn;
            bool x0v = (unsigned)ix       < (unsigned)Wn;
            bool x1v = (unsigned)(ix + 1) < (unsigned)Wn;
            float v00 = (y0v && x0v) ? xc[iy * Wn + ix]           : 0.f;
            float v01 = (y0v && x1v) ? xc[iy * Wn + ix + 1]       : 0.f;
            float v10 = (y1v && x0v) ? xc[(iy + 1) * Wn + ix]     : 0.f;
            float v11 = (y1v && x1v) ? xc[(iy + 1) * Wn + ix + 1] : 0.f;
            s_tile[c][w] = (1.f - fy) * ((1.f - fx) * v00 + fx * v01)
                         +        fy  * ((1.f - fx) * v10 + fx * v11);
        }
        __syncthreads();

        // ---- contraction: acc[i][j] += wT[gk][c][i*32+tcol] * s[c][trow*8+j]
        const float* wgk = wT + (size_t)gk * (CPG * COUT);
        for (int c0 = 0; c0 < CPG; c0 += 4) {
            float wv[4][8];
#pragma unroll
            for (int u = 0; u < 4; u++)
#pragma unroll
                for (int i = 0; i < 8; i++)
                    wv[u][i] = wgk[(c0 + u) * COUT + i * 32 + tcol];
#pragma unroll
            for (int u = 0; u < 4; u++) {
                float4 sA = *(const float4*)&s_tile[c0 + u][trow * 8];
                float4 sB = *(const float4*)&s_tile[c0 + u][trow * 8 + 4];
                float sv[8] = {sA.x, sA.y, sA.z, sA.w, sB.x, sB.y, sB.z, sB.w};
#pragma unroll
                for (int i = 0; i < 8; i++)
#pragma unroll
                    for (int j = 0; j < 8; j++)
                        acc[i][j] = fmaf(wv[u][i], sv[j], acc[i][j]);
            }
        }
        __syncthreads();
    }

    // ---- epilogue: o = i*32+tcol, w = trow*8 + j ----
#pragma unroll
    for (int i = 0; i < 8; i++) {
        int o = i * 32 + tcol;
        float* op = out + (((size_t)b * COUT + o) * Hn + h) * Wn + trow * 8;
        float4 v0, v1;
        v0.x = fmaxf(acc[i][0], 0.f); v0.y = fmaxf(acc[i][1], 0.f);
        v0.z = fmaxf(acc[i][2], 0.f); v0.w = fmaxf(acc[i][3], 0.f);
        v1.x = fmaxf(acc[i][4], 0.f); v1.y = fmaxf(acc[i][5], 0.f);
        v1.z = fmaxf(acc[i][6], 0.f); v1.w = fmaxf(acc[i][7], 0.f);
        *(float4*)op       = v0;
        *(float4*)(op + 4) = v1;
    }
}

// ---------------------------------------------------------------------------
extern "C" void kernel_launch(void* const* d_in, const int* in_sizes, int n_in,
                              void* d_out, int out_size, void* d_ws, size_t ws_size,
                              hipStream_t stream) {
    const float* x     = (const float*)d_in[0];
    const float* shp   = (const float*)d_in[1];
    const float* w_off = (const float*)d_in[2];
    const float* w_def = (const float*)d_in[3];
    float* out = (float*)d_out;
    float* wT  = (float*)d_ws;           // 36*64*256 floats = 2.36 MB

    int nT = GK * CPG * COUT;
    fa_wtrans<<<(nT + 255) / 256, 256, 0, stream>>>(w_def, wT);
    fa_main<<<Bn * Hn, 256, 0, stream>>>(x, shp, w_off, wT, out);
}

// Round 2
// 298.799 us; speedup vs baseline: 2.4454x; 2.4454x over previous
//
#include <hip/hip_runtime.h>
#include <hip/hip_bf16.h>

// FeatureAlign: deformable 3x3 conv, G=4 offset groups, PAD=1.
//   x:(8,256,64,64)f32  shape:(8,4,64,64)f32  w_offset:(72,4)f32
//   w_deform:(256,256,3,3)f32  out:(8,256,64,64)f32 relu
//
// R2: contraction on bf16 MFMA (16x16x32). Per (b,h) block: GEMM
// out[256][64] = sum_{gk,c} w[gk,c][o] * sampled[gk,c][w], K=2304.
// Weights pre-swizzled to fragment-linear bf16 (coalesced A-frag loads from
// L2). Sampled tile bf16 in LDS, XOR-swizzled (bank-uniform b128 access),
// double-buffered, 1 barrier per gk.

#define Bn   8
#define CIN  256
#define COUT 256
#define Hn   64
#define Wn   64
#define Gn   4
#define Kn   9
#define CPG  64
#define GK   36

typedef __bf16 bf16x8 __attribute__((ext_vector_type(8)));
typedef float  f32x4  __attribute__((ext_vector_type(4)));

// ---------------------------------------------------------------------------
// Prep: w_deform (o, g*64+c, ky, kx) -> fragment-linear bf16:
//   wfrag[((gk*16 + mt)*2 + ks)*512 + lane*8 + j]
//   where o = mt*16 + (lane&15), c = ks*32 + (lane>>4)*8 + j
// ---------------------------------------------------------------------------
__global__ void fa_wprep(const float* __restrict__ w, __bf16* __restrict__ wfrag) {
    int i = blockIdx.x * 256 + threadIdx.x;       // 36*16*2*64*8 = 589824
    if (i >= GK * 16 * 2 * 512) return;
    int j    = i & 7;
    int lane = (i >> 3) & 63;
    int ks   = (i >> 9) & 1;
    int mt   = (i >> 10) & 15;
    int gk   = i >> 14;
    int g = gk / Kn, k = gk - g * Kn;
    int o = mt * 16 + (lane & 15);
    int c = ks * 32 + (lane >> 4) * 8 + j;
    float v = w[(size_t)(o * CIN + g * CPG + c) * Kn + k];
    wfrag[i] = (__bf16)v;
}

// ---------------------------------------------------------------------------
__global__ __launch_bounds__(256, 2)
void fa_main(const float* __restrict__ x, const float* __restrict__ shp,
             const float* __restrict__ w_off, const __bf16* __restrict__ wfrag,
             float* __restrict__ out) {
    const int blk = blockIdx.x;               // b*64 + h
    const int b = blk >> 6, h = blk & 63;
    const int t = threadIdx.x;
    const int wid  = t >> 6;                  // wave id: o-stripe of 64
    const int lane = t & 63;
    const int col  = lane & 15;
    const int quad = lane >> 4;

    __shared__ int   s_iyx[GK][Wn];
    __shared__ float s_fy[GK][Wn];
    __shared__ float s_fx[GK][Wn];
    __shared__ __align__(16) __bf16 sB[2][Wn * CPG];  // swizzled [w][c]

    // ---- meta: offsets for all 36 (g,k) x 64 w ----
    for (int i = t; i < GK * Wn; i += 256) {
        int gk = i >> 6, w = i & 63;
        int g = gk / Kn, k = gk - g * Kn;
        int ky = k / 3, kx = k - ky * 3;
        int oy = (g * Kn + k) * 2;
        float dy = 0.f, dx = 0.f;
#pragma unroll
        for (int c = 0; c < 4; c++) {
            float sv = shp[((b * 4 + c) * Hn + h) * Wn + w];
            dy = fmaf(w_off[(oy    ) * 4 + c], sv, dy);
            dx = fmaf(w_off[(oy + 1) * 4 + c], sv, dx);
        }
        float py = (float)(h + ky - 1) + dy;
        float px = (float)(w + kx - 1) + dx;
        float y0 = floorf(py), x0 = floorf(px);
        s_fy[gk][w] = py - y0;
        s_fx[gk][w] = px - x0;
        s_iyx[gk][w] = (((int)y0 & 0xffff) << 16) | ((int)x0 & 0xffff);
    }

    // ---- staging: build swizzled bf16 tile s[w][c] for one gk ----
    auto stage = [&](int gk, int buf) {
        int g = gk / Kn;
        const float* xg = x + (((size_t)b * CIN + g * CPG) << 12);
#pragma unroll
        for (int task = t; task < 512; task += 256) {
            int cblk = task >> 6, w = task & 63;
            int pk = s_iyx[gk][w];
            int iy = pk >> 16;
            int ix = (pk << 16) >> 16;
            float fy = s_fy[gk][w], fx = s_fx[gk][w];
            bool y0v = (unsigned)iy       < (unsigned)Hn;
            bool y1v = (unsigned)(iy + 1) < (unsigned)Hn;
            bool x0v = (unsigned)ix       < (unsigned)Wn;
            bool x1v = (unsigned)(ix + 1) < (unsigned)Wn;
            int yc0 = min(max(iy, 0), Hn - 1), yc1 = min(max(iy + 1, 0), Hn - 1);
            int xc0 = min(max(ix, 0), Wn - 1), xc1 = min(max(ix + 1, 0), Wn - 1);
            int l00 = yc0 * Wn + xc0, l01 = yc0 * Wn + xc1;
            int l10 = yc1 * Wn + xc0, l11 = yc1 * Wn + xc1;
            float wy1 = fy, wy0 = 1.f - fy, wx1 = fx, wx0 = 1.f - fx;
            float w00 = (y0v && x0v) ? wy0 * wx0 : 0.f;
            float w01 = (y0v && x1v) ? wy0 * wx1 : 0.f;
            float w10 = (y1v && x0v) ? wy1 * wx0 : 0.f;
            float w11 = (y1v && x1v) ? wy1 * wx1 : 0.f;
            const float* xc = xg + ((size_t)cblk << 3) * 4096;
            bf16x8 v;
#pragma unroll
            for (int j = 0; j < 8; j++) {
                const float* p = xc + (size_t)j * 4096;
                float s = w00 * p[l00] + w01 * p[l01] + w10 * p[l10] + w11 * p[l11];
                v[j] = (__bf16)s;
            }
            *(bf16x8*)&sB[buf][(size_t)(w * 8 + (cblk ^ (w & 7))) * 8] = v;
        }
    };

    f32x4 acc[4][4];
#pragma unroll
    for (int mt = 0; mt < 4; mt++)
#pragma unroll
        for (int nt = 0; nt < 4; nt++) acc[mt][nt] = (f32x4){0.f, 0.f, 0.f, 0.f};

    __syncthreads();
    stage(0, 0);
    __syncthreads();

    for (int gk = 0; gk < GK; gk++) {
        if (gk + 1 < GK) stage(gk + 1, (gk + 1) & 1);

        // ---- consume buf = gk&1: 2 K-steps x (4 A-frag, 4 B-frag, 16 MFMA)
        int buf = gk & 1;
        const __bf16* wbase = wfrag + (((size_t)gk * 16 + wid * 4) * 2) * 512;
#pragma unroll
        for (int ks = 0; ks < 2; ks++) {
            bf16x8 af[4], bfv[4];
#pragma unroll
            for (int mt = 0; mt < 4; mt++)
                af[mt] = *(const bf16x8*)(wbase + ((size_t)(mt * 2 + ks) * 64 + lane) * 8);
#pragma unroll
            for (int nt = 0; nt < 4; nt++) {
                int w = nt * 16 + col;
                int cblk = ks * 4 + quad;
                bfv[nt] = *(const bf16x8*)&sB[buf][(size_t)(w * 8 + (cblk ^ (w & 7))) * 8];
            }
#pragma unroll
            for (int mt = 0; mt < 4; mt++)
#pragma unroll
                for (int nt = 0; nt < 4; nt++)
                    acc[mt][nt] = __builtin_amdgcn_mfma_f32_16x16x32_bf16(
                        af[mt], bfv[nt], acc[mt][nt], 0, 0, 0);
        }
        __syncthreads();
    }

    // ---- epilogue: D[row = quad*4+r][col], o = wid*64 + mt*16 + row ----
#pragma unroll
    for (int mt = 0; mt < 4; mt++) {
#pragma unroll
        for (int r = 0; r < 4; r++) {
            int o = wid * 64 + mt * 16 + quad * 4 + r;
            float* rowp = out + (((size_t)b * COUT + o) * Hn + h) * Wn;
#pragma unroll
            for (int nt = 0; nt < 4; nt++)
                rowp[nt * 16 + col] = fmaxf(acc[mt][nt][r], 0.f);
        }
    }
}

// ---------------------------------------------------------------------------
extern "C" void kernel_launch(void* const* d_in, const int* in_sizes, int n_in,
                              void* d_out, int out_size, void* d_ws, size_t ws_size,
                              hipStream_t stream) {
    const float* x     = (const float*)d_in[0];
    const float* shp   = (const float*)d_in[1];
    const float* w_off = (const float*)d_in[2];
    const float* w_def = (const float*)d_in[3];
    float* out = (float*)d_out;
    __bf16* wfrag = (__bf16*)d_ws;         // 589824 bf16 = 1.18 MB

    int nT = GK * 16 * 2 * 512;
    fa_wprep<<<(nT + 255) / 256, 256, 0, stream>>>(w_def, wfrag);
    fa_main<<<Bn * Hn, 256, 0, stream>>>(x, shp, w_off, wfrag, out);
}

// Round 3
// 160.946 us; speedup vs baseline: 4.5399x; 1.8565x over previous
//
#include <hip/hip_runtime.h>
#include <hip/hip_bf16.h>

// FeatureAlign deformable 3x3 conv, G=4, PAD=1.
// R3: x pre-transposed to NHWC bf16 -> each bilinear corner is ONE b128 load
// covering 8 channels (was 8 scalar loads). Block per (b,h,w-half): 1024
// blocks, 4 blocks/CU (16 waves/CU) for latency hiding. Issue order per gk:
// A-frags(gk) -> corners(gk+1) -> MFMA (vmcnt leaves corners in flight) ->
// interp+LDS write -> barrier.

#define Bn   8
#define CIN  256
#define COUT 256
#define Hn   64
#define Wn   64
#define Gn   4
#define Kn   9
#define CPG  64
#define GK   36

typedef __bf16 bf16x8 __attribute__((ext_vector_type(8)));
typedef float  f32x4  __attribute__((ext_vector_type(4)));

// ---------------------------------------------------------------------------
// x (b,c,y,x) f32 -> xt (b, y*64+x, c) bf16    [NHWC]
// ---------------------------------------------------------------------------
__global__ void fa_xprep(const float* __restrict__ x, __bf16* __restrict__ xt) {
    const int b = blockIdx.x >> 6, tile = blockIdx.x & 63;
    const int hw0 = tile * 64;
    const int t = threadIdx.x;
    __shared__ __bf16 sm[64][264];          // [hw][c], padded
    const int hw4 = t & 15, cq = t >> 4;
#pragma unroll
    for (int it = 0; it < 16; it++) {
        int c = it * 16 + cq;
        float4 v = *(const float4*)&x[((size_t)(b * CIN + c)) * 4096 + hw0 + hw4 * 4];
        sm[hw4 * 4 + 0][c] = (__bf16)v.x;
        sm[hw4 * 4 + 1][c] = (__bf16)v.y;
        sm[hw4 * 4 + 2][c] = (__bf16)v.z;
        sm[hw4 * 4 + 3][c] = (__bf16)v.w;
    }
    __syncthreads();
#pragma unroll
    for (int j = 0; j < 8; j++) {
        int hw = j * 8 + (t >> 5), seg = t & 31;
        bf16x8 v;
#pragma unroll
        for (int u = 0; u < 8; u++) v[u] = sm[hw][seg * 8 + u];
        *(bf16x8*)&xt[((size_t)b * 4096 + hw0 + hw) * 256 + seg * 8] = v;
    }
}

// ---------------------------------------------------------------------------
// w_deform (o, g*64+c, ky, kx) -> fragment-linear bf16 (same as R2)
//   wfrag[((gk*16+mt)*2+ks)*512 + lane*8 + j]; o=mt*16+(lane&15),
//   c=ks*32+(lane>>4)*8+j
// ---------------------------------------------------------------------------
__global__ void fa_wprep(const float* __restrict__ w, __bf16* __restrict__ wfrag) {
    int i = blockIdx.x * 256 + threadIdx.x;
    if (i >= GK * 16 * 2 * 512) return;
    int j    = i & 7;
    int lane = (i >> 3) & 63;
    int ks   = (i >> 9) & 1;
    int mt   = (i >> 10) & 15;
    int gk   = i >> 14;
    int g = gk / Kn, k = gk - g * Kn;
    int o = mt * 16 + (lane & 15);
    int c = ks * 32 + (lane >> 4) * 8 + j;
    wfrag[i] = (__bf16)w[(size_t)(o * CIN + g * CPG + c) * Kn + k];
}

// ---------------------------------------------------------------------------
__global__ __launch_bounds__(256, 4)
void fa_main(const __bf16* __restrict__ xt, const float* __restrict__ shp,
             const float* __restrict__ w_off, const __bf16* __restrict__ wfrag,
             float* __restrict__ out) {
    const int blk = blockIdx.x;                 // b*128 + h*2 + wh
    const int b = blk >> 7, h = (blk >> 1) & 63, wh = blk & 1;
    const int w0 = wh * 32;
    const int t = threadIdx.x;
    const int wid = t >> 6, lane = t & 63;
    const int col = lane & 15, quad = lane >> 4;
    const int cg = t & 7, wl = t >> 3;          // staging: 8 c-groups x 32 w

    __shared__ int   s_iyx[GK * 32];
    __shared__ float s_fy[GK * 32];
    __shared__ float s_fx[GK * 32];
    __shared__ __align__(16) __bf16 sB[2][32 * 64];   // [w][c] xor-swizzled

    // ---- meta for this block's 32 w columns ----
    for (int i = t; i < GK * 32; i += 256) {
        int gk = i >> 5, w = (i & 31) + w0;
        int g = gk / Kn, k = gk - g * Kn;
        int ky = k / 3, kx = k - ky * 3;
        int oy = (g * Kn + k) * 2;
        float dy = 0.f, dx = 0.f;
#pragma unroll
        for (int c = 0; c < 4; c++) {
            float sv = shp[((b * 4 + c) * Hn + h) * Wn + w];
            dy = fmaf(w_off[(oy    ) * 4 + c], sv, dy);
            dx = fmaf(w_off[(oy + 1) * 4 + c], sv, dx);
        }
        float py = (float)(h + ky - 1) + dy;
        float px = (float)(w + kx - 1) + dx;
        float y0 = floorf(py), x0 = floorf(px);
        s_fy[i] = py - y0;
        s_fx[i] = px - x0;
        s_iyx[i] = (((int)y0 & 0xffff) << 16) | ((int)x0 & 0xffff);
    }

    const __bf16* xb = xt + (size_t)b * 4096 * 256;

    // issue 4 corner b128 loads for (gk, this thread's (cg,wl)); weights out
    auto issue = [&](int gk, bf16x8* c4, float* w4) {
        int m = gk * 32 + wl;
        int g = gk / Kn;
        int pk = s_iyx[m];
        int iy = pk >> 16, ix = (pk << 16) >> 16;
        float fy = s_fy[m], fx = s_fx[m];
        bool y0v = (unsigned)iy       < (unsigned)Hn;
        bool y1v = (unsigned)(iy + 1) < (unsigned)Hn;
        bool x0v = (unsigned)ix       < (unsigned)Wn;
        bool x1v = (unsigned)(ix + 1) < (unsigned)Wn;
        int yc0 = min(max(iy, 0), Hn - 1), yc1 = min(max(iy + 1, 0), Hn - 1);
        int xc0 = min(max(ix, 0), Wn - 1), xc1 = min(max(ix + 1, 0), Wn - 1);
        const __bf16* base = xb + g * CPG + cg * 8;
        c4[0] = *(const bf16x8*)(base + ((size_t)(yc0 * 64 + xc0)) * 256);
        c4[1] = *(const bf16x8*)(base + ((size_t)(yc0 * 64 + xc1)) * 256);
        c4[2] = *(const bf16x8*)(base + ((size_t)(yc1 * 64 + xc0)) * 256);
        c4[3] = *(const bf16x8*)(base + ((size_t)(yc1 * 64 + xc1)) * 256);
        float wy1 = fy, wy0 = 1.f - fy, wx1 = fx, wx0 = 1.f - fx;
        w4[0] = (y0v && x0v) ? wy0 * wx0 : 0.f;
        w4[1] = (y0v && x1v) ? wy0 * wx1 : 0.f;
        w4[2] = (y1v && x0v) ? wy1 * wx0 : 0.f;
        w4[3] = (y1v && x1v) ? wy1 * wx1 : 0.f;
    };
    auto commit = [&](const bf16x8* c4, const float* w4, int buf) {
        bf16x8 r;
#pragma unroll
        for (int j = 0; j < 8; j++) {
            float v = w4[0] * (float)c4[0][j] + w4[1] * (float)c4[1][j]
                    + w4[2] * (float)c4[2][j] + w4[3] * (float)c4[3][j];
            r[j] = (__bf16)v;
        }
        *(bf16x8*)&sB[buf][(wl * 8 + (cg ^ (wl & 7))) * 8] = r;
    };

    f32x4 acc[4][2];
#pragma unroll
    for (int mt = 0; mt < 4; mt++)
#pragma unroll
        for (int nt = 0; nt < 2; nt++) acc[mt][nt] = (f32x4){0.f, 0.f, 0.f, 0.f};

    __syncthreads();

    {   // prologue: fully stage gk=0 into buf 0
        bf16x8 c4[4]; float w4[4];
        issue(0, c4, w4);
        commit(c4, w4, 0);
    }
    __syncthreads();

    bf16x8 c4[4]; float w4[4];
    for (int gk = 0; gk < GK; gk++) {
        const int buf = gk & 1;
        // 1) A-frags for THIS gk (issued first so MFMA's wait leaves the
        //    corner loads below still in flight)
        const __bf16* wbase = wfrag + (((size_t)gk * 16 + wid * 4) * 2) * 512;
        bf16x8 af[2][4];
#pragma unroll
        for (int ks = 0; ks < 2; ks++)
#pragma unroll
            for (int mt = 0; mt < 4; mt++)
                af[ks][mt] = *(const bf16x8*)(wbase + ((size_t)(mt * 2 + ks) * 64 + lane) * 8);
        // 2) corner loads for gk+1
        if (gk + 1 < GK) issue(gk + 1, c4, w4);
        // 3) MFMA on buf
#pragma unroll
        for (int ks = 0; ks < 2; ks++) {
            bf16x8 bfv[2];
#pragma unroll
            for (int nt = 0; nt < 2; nt++) {
                int w = nt * 16 + col;
                int cq8 = ks * 4 + quad;
                bfv[nt] = *(const bf16x8*)&sB[buf][(w * 8 + (cq8 ^ (w & 7))) * 8];
            }
#pragma unroll
            for (int mt = 0; mt < 4; mt++)
#pragma unroll
                for (int nt = 0; nt < 2; nt++)
                    acc[mt][nt] = __builtin_amdgcn_mfma_f32_16x16x32_bf16(
                        af[ks][mt], bfv[nt], acc[mt][nt], 0, 0, 0);
        }
        // 4) interp + write other buffer
        if (gk + 1 < GK) commit(c4, w4, buf ^ 1);
        __syncthreads();
    }

    // ---- epilogue ----
#pragma unroll
    for (int mt = 0; mt < 4; mt++)
#pragma unroll
        for (int r = 0; r < 4; r++) {
            int o = wid * 64 + mt * 16 + quad * 4 + r;
            float* rowp = out + (((size_t)b * COUT + o) * Hn + h) * Wn + w0;
#pragma unroll
            for (int nt = 0; nt < 2; nt++)
                rowp[nt * 16 + col] = fmaxf(acc[mt][nt][r], 0.f);
        }
}

// ---------------------------------------------------------------------------
extern "C" void kernel_launch(void* const* d_in, const int* in_sizes, int n_in,
                              void* d_out, int out_size, void* d_ws, size_t ws_size,
                              hipStream_t stream) {
    const float* x     = (const float*)d_in[0];
    const float* shp   = (const float*)d_in[1];
    const float* w_off = (const float*)d_in[2];
    const float* w_def = (const float*)d_in[3];
    float* out = (float*)d_out;
    __bf16* wfrag = (__bf16*)d_ws;                         // 1.18 MB
    __bf16* xt    = (__bf16*)((char*)d_ws + (2u << 20));   // 16.8 MB

    fa_xprep<<<Bn * 64, 256, 0, stream>>>(x, xt);
    int nT = GK * 16 * 2 * 512;
    fa_wprep<<<(nT + 255) / 256, 256, 0, stream>>>(w_def, wfrag);
    fa_main<<<Bn * Hn * 2, 256, 0, stream>>>(xt, shp, w_off, wfrag, out);
}

// Round 4
// 154.731 us; speedup vs baseline: 4.7223x; 1.0402x over previous
//
#include <hip/hip_runtime.h>
#include <hip/hip_bf16.h>

// FeatureAlign deformable 3x3 conv, G=4, PAD=1.
// R4: batch folded into GEMM N-dim (N=64 = 2b x 32w) -> 512 blocks -> weight
// L2 traffic halved (was the binding pipe at ~65% of 34.5 TB/s). Corner
// loads prefetched 2 gk ahead (full-iteration latency cover for 2 blocks/CU).
// Prep fused into one LDS-free kernel.

#define Bn   8
#define CIN  256
#define COUT 256
#define Hn   64
#define Wn   64
#define Gn   4
#define Kn   9
#define CPG  64
#define GK   36

typedef __bf16 bf16x8 __attribute__((ext_vector_type(8)));
typedef float  f32x4  __attribute__((ext_vector_type(4)));

// ---------------------------------------------------------------------------
// Fused prep.
//  blocks [0, 4096):   x (b,c,y,x) f32 -> xt (b, y*64+x, c) bf16  [NHWC]
//  blocks [4096, 6400): w_deform -> fragment-linear bf16 wfrag
//   wfrag[((gk*16+mt)*2+ks)*512 + lane*8 + j]; o=mt*16+(lane&15),
//   c=ks*32+(lane>>4)*8+j
// ---------------------------------------------------------------------------
__global__ void fa_prep(const float* __restrict__ x, const float* __restrict__ w,
                        __bf16* __restrict__ xt, __bf16* __restrict__ wfrag) {
    const int bid = blockIdx.x, t = threadIdx.x;
    if (bid < 4096) {
        // xt: bid = b*512 + hwt*8 + c8q ; thread: hw=hwt*64+(t&63), c8=c8q*4+(t>>6)
        const int c8q = bid & 7, hwt = (bid >> 3) & 63, b = bid >> 9;
        const int hw = hwt * 64 + (t & 63);
        const int c8 = c8q * 4 + (t >> 6);
        const float* xp = x + ((size_t)(b * CIN + c8 * 8) << 12) + hw;
        bf16x8 v;
#pragma unroll
        for (int j = 0; j < 8; j++) v[j] = (__bf16)xp[(size_t)j << 12];
        *(bf16x8*)&xt[(((size_t)b << 12) + hw) * 256 + c8 * 8] = v;
    } else {
        int i = (bid - 4096) * 256 + t;
        int j    = i & 7;
        int lane = (i >> 3) & 63;
        int ks   = (i >> 9) & 1;
        int mt   = (i >> 10) & 15;
        int gk   = i >> 14;
        int g = gk / Kn, k = gk - g * Kn;
        int o = mt * 16 + (lane & 15);
        int c = ks * 32 + (lane >> 4) * 8 + j;
        wfrag[i] = (__bf16)w[(size_t)(o * CIN + g * CPG + c) * Kn + k];
    }
}

// ---------------------------------------------------------------------------
// Main: block = bp*128 + h*2 + wh. N-columns n = bb*32 + wl (b = bp*2+bb,
// w = wh*32 + wl). GEMM out[256 o][64 n] over K = 36*64.
// ---------------------------------------------------------------------------
__global__ __launch_bounds__(256, 2)
void fa_main(const __bf16* __restrict__ xt, const float* __restrict__ shp,
             const float* __restrict__ w_off, const __bf16* __restrict__ wfrag,
             float* __restrict__ out) {
    const int blk = blockIdx.x;                 // bp*128 + h*2 + wh
    const int bp = blk >> 7, h = (blk >> 1) & 63, wh = blk & 1;
    const int w0 = wh * 32;
    const int t = threadIdx.x;
    const int wid = t >> 6, lane = t & 63;
    const int col = lane & 15, quad = lane >> 4;
    const int cg = t & 7, nl0 = t >> 3;         // staging: 8 cg x 32 n, x2 tasks

    __shared__ int   s_iyx[GK * 64];
    __shared__ float s_fy[GK * 64];
    __shared__ float s_fx[GK * 64];
    __shared__ __align__(16) __bf16 sB[2][64 * 64];   // [n][c] xor-swizzled

    // ---- meta: (gk, n) for n = bb*32 + wl ----
    for (int i = t; i < GK * 64; i += 256) {
        int gk = i >> 6, n = i & 63;
        int bb = n >> 5, w = w0 + (n & 31);
        int b = bp * 2 + bb;
        int g = gk / Kn, k = gk - g * Kn;
        int ky = k / 3, kx = k - ky * 3;
        int oy = (g * Kn + k) * 2;
        float dy = 0.f, dx = 0.f;
#pragma unroll
        for (int c = 0; c < 4; c++) {
            float sv = shp[((b * 4 + c) * Hn + h) * Wn + w];
            dy = fmaf(w_off[(oy    ) * 4 + c], sv, dy);
            dx = fmaf(w_off[(oy + 1) * 4 + c], sv, dx);
        }
        float py = (float)(h + ky - 1) + dy;
        float px = (float)(w + kx - 1) + dx;
        float y0 = floorf(py), x0 = floorf(px);
        s_fy[i] = py - y0;
        s_fx[i] = px - x0;
        s_iyx[i] = (((int)y0 & 0xffff) << 16) | ((int)x0 & 0xffff);
    }

    // per-thread staging state: 2 tasks (n = nl0, nl0+32), 4 corners each
    bf16x8 c4[2][4];
    float  w4[2][4];

    auto issue = [&](int gk) {
#pragma unroll
        for (int s = 0; s < 2; s++) {
            int n = nl0 + s * 32;
            int bb = n >> 5;
            int b = bp * 2 + bb;
            int m = gk * 64 + n;
            int g = gk / Kn;
            int pk = s_iyx[m];
            int iy = pk >> 16, ix = (pk << 16) >> 16;
            float fy = s_fy[m], fx = s_fx[m];
            bool y0v = (unsigned)iy       < (unsigned)Hn;
            bool y1v = (unsigned)(iy + 1) < (unsigned)Hn;
            bool x0v = (unsigned)ix       < (unsigned)Wn;
            bool x1v = (unsigned)(ix + 1) < (unsigned)Wn;
            int yc0 = min(max(iy, 0), Hn - 1), yc1 = min(max(iy + 1, 0), Hn - 1);
            int xc0 = min(max(ix, 0), Wn - 1), xc1 = min(max(ix + 1, 0), Wn - 1);
            const __bf16* base = xt + (((size_t)b << 12)) * 256 + g * CPG + cg * 8;
            c4[s][0] = *(const bf16x8*)(base + ((size_t)(yc0 * 64 + xc0)) * 256);
            c4[s][1] = *(const bf16x8*)(base + ((size_t)(yc0 * 64 + xc1)) * 256);
            c4[s][2] = *(const bf16x8*)(base + ((size_t)(yc1 * 64 + xc0)) * 256);
            c4[s][3] = *(const bf16x8*)(base + ((size_t)(yc1 * 64 + xc1)) * 256);
            float wy1 = fy, wy0 = 1.f - fy, wx1 = fx, wx0 = 1.f - fx;
            w4[s][0] = (y0v && x0v) ? wy0 * wx0 : 0.f;
            w4[s][1] = (y0v && x1v) ? wy0 * wx1 : 0.f;
            w4[s][2] = (y1v && x0v) ? wy1 * wx0 : 0.f;
            w4[s][3] = (y1v && x1v) ? wy1 * wx1 : 0.f;
        }
    };
    auto commit = [&](int buf) {
#pragma unroll
        for (int s = 0; s < 2; s++) {
            int n = nl0 + s * 32;
            bf16x8 r;
#pragma unroll
            for (int j = 0; j < 8; j++) {
                float v = w4[s][0] * (float)c4[s][0][j] + w4[s][1] * (float)c4[s][1][j]
                        + w4[s][2] * (float)c4[s][2][j] + w4[s][3] * (float)c4[s][3][j];
                r[j] = (__bf16)v;
            }
            *(bf16x8*)&sB[buf][(n * 8 + (cg ^ (n & 7))) * 8] = r;
        }
    };

    f32x4 acc[4][4];
#pragma unroll
    for (int mt = 0; mt < 4; mt++)
#pragma unroll
        for (int nt = 0; nt < 4; nt++) acc[mt][nt] = (f32x4){0.f, 0.f, 0.f, 0.f};

    __syncthreads();            // meta visible

    issue(0);
    commit(0);                  // sB[0] = tile(gk 0)
    issue(1);                   // corners(gk 1) in regs
    __syncthreads();

    for (int gk = 0; gk < GK; gk++) {
        const int buf = gk & 1;
        // 1) A-frags for THIS gk (oldest vm loads -> MFMA's wait leaves the
        //    corner loads below in flight)
        const __bf16* wbase = wfrag + (((size_t)gk * 16 + wid * 4) * 2) * 512;
        bf16x8 af[2][4];
#pragma unroll
        for (int ks = 0; ks < 2; ks++)
#pragma unroll
            for (int mt = 0; mt < 4; mt++)
                af[ks][mt] = *(const bf16x8*)(wbase + ((size_t)(mt * 2 + ks) * 64 + lane) * 8);
        // 2) interp gk+1 from regs (landed last iter) -> other buffer
        if (gk + 1 < GK) commit(buf ^ 1);
        // 3) corner loads for gk+2 (reuse regs; in flight across MFMA+barrier)
        if (gk + 2 < GK) issue(gk + 2);
        // 4) MFMA on buf
#pragma unroll
        for (int ks = 0; ks < 2; ks++) {
            bf16x8 bfv[4];
#pragma unroll
            for (int nt = 0; nt < 4; nt++) {
                int n = nt * 16 + col;
                int cq8 = ks * 4 + quad;
                bfv[nt] = *(const bf16x8*)&sB[buf][(n * 8 + (cq8 ^ (n & 7))) * 8];
            }
#pragma unroll
            for (int mt = 0; mt < 4; mt++)
#pragma unroll
                for (int nt = 0; nt < 4; nt++)
                    acc[mt][nt] = __builtin_amdgcn_mfma_f32_16x16x32_bf16(
                        af[ks][mt], bfv[nt], acc[mt][nt], 0, 0, 0);
        }
        __syncthreads();
    }

    // ---- epilogue: o = wid*64 + mt*16 + quad*4 + r ; n = nt*16 + col ----
#pragma unroll
    for (int mt = 0; mt < 4; mt++)
#pragma unroll
        for (int r = 0; r < 4; r++) {
            int o = wid * 64 + mt * 16 + quad * 4 + r;
#pragma unroll
            for (int nt = 0; nt < 4; nt++) {
                int n = nt * 16 + col;
                int b = bp * 2 + (n >> 5);
                int w = w0 + (n & 31);
                out[(((size_t)(b * COUT + o)) << 12) + h * Wn + w] =
                    fmaxf(acc[mt][nt][r], 0.f);
            }
        }
}

// ---------------------------------------------------------------------------
extern "C" void kernel_launch(void* const* d_in, const int* in_sizes, int n_in,
                              void* d_out, int out_size, void* d_ws, size_t ws_size,
                              hipStream_t stream) {
    const float* x     = (const float*)d_in[0];
    const float* shp   = (const float*)d_in[1];
    const float* w_off = (const float*)d_in[2];
    const float* w_def = (const float*)d_in[3];
    float* out = (float*)d_out;
    __bf16* wfrag = (__bf16*)d_ws;                         // 1.18 MB
    __bf16* xt    = (__bf16*)((char*)d_ws + (2u << 20));   // 16.8 MB

    fa_prep<<<4096 + 2304, 256, 0, stream>>>(x, w_def, xt, wfrag);
    fa_main<<<512, 256, 0, stream>>>(xt, shp, w_off, wfrag, out);
}

// Round 5
// 154.313 us; speedup vs baseline: 4.7351x; 1.0027x over previous
//
#include <hip/hip_runtime.h>
#include <hip/hip_bf16.h>

// FeatureAlign deformable 3x3 conv, G=4, PAD=1.
// R5: latency-bound at 2 waves/SIMD (grid-capped) -> pipeline deeper in-wave:
// A-fragments register-double-buffered via gk-unroll-by-2 (A(gk+1) in flight
// across MFMA(gk)); corners stay prefetched 2 gk ahead. wprep rewritten with
// coalesced reads + LDS transpose (was stride-9216B scalar gathers).

#define Bn   8
#define CIN  256
#define COUT 256
#define Hn   64
#define Wn   64
#define Gn   4
#define Kn   9
#define CPG  64
#define GK   36

typedef __bf16 bf16x8 __attribute__((ext_vector_type(8)));
typedef float  f32x4  __attribute__((ext_vector_type(4)));

// ---------------------------------------------------------------------------
// Fused prep.
//  blocks [0, 4096):        x (b,c,y,x) f32 -> xt (b, y*64+x, c) bf16 [NHWC]
//  blocks [4096, 4096+32):  w_deform -> fragment-linear bf16 wfrag
//    wfrag[((gk*16+mt)*2+ks)*512 + lane*8 + j]; o=mt*16+(lane&15),
//    c=ks*32+(lane>>4)*8+j.  Block = (mt, g-pair): coalesced row reads,
//    LDS transpose (padded), contiguous lane-stripe writes.
// ---------------------------------------------------------------------------
#define SWPAD 1156            // LDS row stride (bf16): 1152+4 -> banks spread
__global__ void fa_prep(const float* __restrict__ x, const float* __restrict__ w,
                        __bf16* __restrict__ xt, __bf16* __restrict__ wfrag) {
    const int bid = blockIdx.x, t = threadIdx.x;
    __shared__ __bf16 sw[16 * SWPAD];
    if (bid < 4096) {
        const int c8q = bid & 7, hwt = (bid >> 3) & 63, b = bid >> 9;
        const int hw = hwt * 64 + (t & 63);
        const int c8 = c8q * 4 + (t >> 6);
        const float* xp = x + ((size_t)(b * CIN + c8 * 8) << 12) + hw;
        bf16x8 v;
#pragma unroll
        for (int j = 0; j < 8; j++) v[j] = (__bf16)xp[(size_t)j << 12];
        *(bf16x8*)&xt[(((size_t)b << 12) + hw) * 256 + c8 * 8] = v;
    } else {
        const int mt = (bid - 4096) >> 1, gh = (bid - 4096) & 1;
        const int o0 = mt * 16, g0 = gh * 2;
        // read: 16 o-rows x 1152 contiguous floats (g0..g0+1 slice), coalesced
        const int r = t >> 4, tr = t & 15;
        const float* wp = w + (size_t)(o0 + r) * (CIN * Kn) + g0 * (CPG * Kn);
#pragma unroll
        for (int it = 0; it < 18; it++) {
            int off = it * 64 + tr * 4;
            float4 v = *(const float4*)(wp + off);
            __bf16* d = &sw[r * SWPAD + off];
            d[0] = (__bf16)v.x; d[1] = (__bf16)v.y;
            d[2] = (__bf16)v.z; d[3] = (__bf16)v.w;
        }
        __syncthreads();
        // write: 2304 chunks (18 gkl x 2 ks x 64 lanes), 9 per thread
#pragma unroll
        for (int it = 0; it < 9; it++) {
            int chunk = it * 256 + t;
            int lane = chunk & 63, ks = (chunk >> 6) & 1, gkl = chunk >> 7;
            int gl = gkl / Kn, k = gkl - gl * Kn;
            int gk = g0 * Kn + gkl;
            int ol = lane & 15;
            int cbase = ks * 32 + (lane >> 4) * 8;
            bf16x8 v;
#pragma unroll
            for (int j = 0; j < 8; j++)
                v[j] = sw[ol * SWPAD + (gl * CPG + cbase + j) * Kn + k];
            *(bf16x8*)&wfrag[(((size_t)gk * 16 + mt) * 2 + ks) * 512 + lane * 8] = v;
        }
    }
}

// ---------------------------------------------------------------------------
// Main: block = bp*128 + h*2 + wh. N = 64 (2 b x 32 w). K = 36*64.
// ---------------------------------------------------------------------------
__global__ __launch_bounds__(256, 2)
void fa_main(const __bf16* __restrict__ xt, const float* __restrict__ shp,
             const float* __restrict__ w_off, const __bf16* __restrict__ wfrag,
             float* __restrict__ out) {
    const int blk = blockIdx.x;
    const int bp = blk >> 7, h = (blk >> 1) & 63, wh = blk & 1;
    const int w0 = wh * 32;
    const int t = threadIdx.x;
    const int wid = t >> 6, lane = t & 63;
    const int col = lane & 15, quad = lane >> 4;
    const int cg = t & 7, nl0 = t >> 3;

    __shared__ int   s_iyx[GK * 64];
    __shared__ float s_fy[GK * 64];
    __shared__ float s_fx[GK * 64];
    __shared__ __align__(16) __bf16 sB[2][64 * 64];   // [n][c] xor-swizzled

    for (int i = t; i < GK * 64; i += 256) {
        int gk = i >> 6, n = i & 63;
        int bb = n >> 5, w = w0 + (n & 31);
        int b = bp * 2 + bb;
        int g = gk / Kn, k = gk - g * Kn;
        int ky = k / 3, kx = k - ky * 3;
        int oy = (g * Kn + k) * 2;
        float dy = 0.f, dx = 0.f;
#pragma unroll
        for (int c = 0; c < 4; c++) {
            float sv = shp[((b * 4 + c) * Hn + h) * Wn + w];
            dy = fmaf(w_off[(oy    ) * 4 + c], sv, dy);
            dx = fmaf(w_off[(oy + 1) * 4 + c], sv, dx);
        }
        float py = (float)(h + ky - 1) + dy;
        float px = (float)(w + kx - 1) + dx;
        float y0 = floorf(py), x0 = floorf(px);
        s_fy[i] = py - y0;
        s_fx[i] = px - x0;
        s_iyx[i] = (((int)y0 & 0xffff) << 16) | ((int)x0 & 0xffff);
    }

    bf16x8 c4[2][4];
    float  w4[2][4];

    auto issue = [&](int gk) {
#pragma unroll
        for (int s = 0; s < 2; s++) {
            int n = nl0 + s * 32;
            int b = bp * 2 + (n >> 5);
            int m = gk * 64 + n;
            int g = gk / Kn;
            int pk = s_iyx[m];
            int iy = pk >> 16, ix = (pk << 16) >> 16;
            float fy = s_fy[m], fx = s_fx[m];
            bool y0v = (unsigned)iy       < (unsigned)Hn;
            bool y1v = (unsigned)(iy + 1) < (unsigned)Hn;
            bool x0v = (unsigned)ix       < (unsigned)Wn;
            bool x1v = (unsigned)(ix + 1) < (unsigned)Wn;
            int yc0 = min(max(iy, 0), Hn - 1), yc1 = min(max(iy + 1, 0), Hn - 1);
            int xc0 = min(max(ix, 0), Wn - 1), xc1 = min(max(ix + 1, 0), Wn - 1);
            const __bf16* base = xt + (((size_t)b << 12)) * 256 + g * CPG + cg * 8;
            c4[s][0] = *(const bf16x8*)(base + ((size_t)(yc0 * 64 + xc0)) * 256);
            c4[s][1] = *(const bf16x8*)(base + ((size_t)(yc0 * 64 + xc1)) * 256);
            c4[s][2] = *(const bf16x8*)(base + ((size_t)(yc1 * 64 + xc0)) * 256);
            c4[s][3] = *(const bf16x8*)(base + ((size_t)(yc1 * 64 + xc1)) * 256);
            float wy1 = fy, wy0 = 1.f - fy, wx1 = fx, wx0 = 1.f - fx;
            w4[s][0] = (y0v && x0v) ? wy0 * wx0 : 0.f;
            w4[s][1] = (y0v && x1v) ? wy0 * wx1 : 0.f;
            w4[s][2] = (y1v && x0v) ? wy1 * wx0 : 0.f;
            w4[s][3] = (y1v && x1v) ? wy1 * wx1 : 0.f;
        }
    };
    auto commit = [&](int buf) {
#pragma unroll
        for (int s = 0; s < 2; s++) {
            int n = nl0 + s * 32;
            bf16x8 r;
#pragma unroll
            for (int j = 0; j < 8; j++) {
                float v = w4[s][0] * (float)c4[s][0][j] + w4[s][1] * (float)c4[s][1][j]
                        + w4[s][2] * (float)c4[s][2][j] + w4[s][3] * (float)c4[s][3][j];
                r[j] = (__bf16)v;
            }
            *(bf16x8*)&sB[buf][(n * 8 + (cg ^ (n & 7))) * 8] = r;
        }
    };
    auto loadA = [&](int gk, bf16x8 af[2][4]) {
        const __bf16* wbase = wfrag + (((size_t)gk * 16 + wid * 4) * 2) * 512;
#pragma unroll
        for (int ks = 0; ks < 2; ks++)
#pragma unroll
            for (int mt = 0; mt < 4; mt++)
                af[ks][mt] = *(const bf16x8*)(wbase + ((size_t)(mt * 2 + ks) * 64 + lane) * 8);
    };

    f32x4 acc[4][4];
#pragma unroll
    for (int mt = 0; mt < 4; mt++)
#pragma unroll
        for (int nt = 0; nt < 4; nt++) acc[mt][nt] = (f32x4){0.f, 0.f, 0.f, 0.f};

    auto domfma = [&](bf16x8 af[2][4], int buf) {
#pragma unroll
        for (int ks = 0; ks < 2; ks++) {
            bf16x8 bfv[4];
#pragma unroll
            for (int nt = 0; nt < 4; nt++) {
                int n = nt * 16 + col;
                int cq8 = ks * 4 + quad;
                bfv[nt] = *(const bf16x8*)&sB[buf][(n * 8 + (cq8 ^ (n & 7))) * 8];
            }
#pragma unroll
            for (int mt = 0; mt < 4; mt++)
#pragma unroll
                for (int nt = 0; nt < 4; nt++)
                    acc[mt][nt] = __builtin_amdgcn_mfma_f32_16x16x32_bf16(
                        af[ks][mt], bfv[nt], acc[mt][nt], 0, 0, 0);
        }
    };

    bf16x8 afA[2][4], afB[2][4];

    __syncthreads();            // meta visible

    loadA(0, afA);
    issue(0);
    commit(0);                  // sB[0] = tile 0
    issue(1);                   // corners(1) in regs
    __syncthreads();

    for (int gk = 0; gk < GK; gk += 2) {
        // ---- even half: consume (afA, sB0) = gk ----
        loadA(gk + 1, afB);                    // in flight across MFMA below
        commit(1);                             // tile gk+1 -> sB1
        if (gk + 2 < GK) issue(gk + 2);        // corners gk+2 in flight
        domfma(afA, 0);
        __syncthreads();
        // ---- odd half: consume (afB, sB1) = gk+1 ----
        if (gk + 2 < GK) loadA(gk + 2, afA);
        if (gk + 2 < GK) commit(0);            // tile gk+2 -> sB0
        if (gk + 3 < GK) issue(gk + 3);
        domfma(afB, 1);
        __syncthreads();
    }

    // ---- epilogue ----
#pragma unroll
    for (int mt = 0; mt < 4; mt++)
#pragma unroll
        for (int r = 0; r < 4; r++) {
            int o = wid * 64 + mt * 16 + quad * 4 + r;
#pragma unroll
            for (int nt = 0; nt < 4; nt++) {
                int n = nt * 16 + col;
                int b = bp * 2 + (n >> 5);
                int w = w0 + (n & 31);
                out[(((size_t)(b * COUT + o)) << 12) + h * Wn + w] =
                    fmaxf(acc[mt][nt][r], 0.f);
            }
        }
}

// ---------------------------------------------------------------------------
extern "C" void kernel_launch(void* const* d_in, const int* in_sizes, int n_in,
                              void* d_out, int out_size, void* d_ws, size_t ws_size,
                              hipStream_t stream) {
    const float* x     = (const float*)d_in[0];
    const float* shp   = (const float*)d_in[1];
    const float* w_off = (const float*)d_in[2];
    const float* w_def = (const float*)d_in[3];
    float* out = (float*)d_out;
    __bf16* wfrag = (__bf16*)d_ws;                         // 1.18 MB
    __bf16* xt    = (__bf16*)((char*)d_ws + (2u << 20));   // 16.8 MB

    fa_prep<<<4096 + 32, 256, 0, stream>>>(x, w_def, xt, wfrag);
    fa_main<<<512, 256, 0, stream>>>(xt, shp, w_off, wfrag, out);
}

// Round 6
// 147.432 us; speedup vs baseline: 4.9561x; 1.0467x over previous
//
#include <hip/hip_runtime.h>
#include <hip/hip_bf16.h>

// FeatureAlign deformable 3x3 conv, G=4, PAD=1.
// R6: same 512-block grid (N=64/block) but 512-thread blocks -> 16 waves/CU
// (4/SIMD, was 2/SIMD): doubles load-in-flight capacity at ZERO L2-traffic
// change. Wave tile 32x64 (2 mt x 4 nt), 1 staging task/thread. R5's A-reg
// double-buffer dropped (proven neutral; saves VGPRs for occupancy).

#define Bn   8
#define CIN  256
#define COUT 256
#define Hn   64
#define Wn   64
#define Gn   4
#define Kn   9
#define CPG  64
#define GK   36

typedef __bf16 bf16x8 __attribute__((ext_vector_type(8)));
typedef float  f32x4  __attribute__((ext_vector_type(4)));

// ---------------------------------------------------------------------------
// Fused prep (unchanged from R5).
//  blocks [0, 4096):        x (b,c,y,x) f32 -> xt (b, y*64+x, c) bf16 [NHWC]
//  blocks [4096, 4096+32):  w_deform -> fragment-linear bf16 wfrag
// ---------------------------------------------------------------------------
#define SWPAD 1156
__global__ void fa_prep(const float* __restrict__ x, const float* __restrict__ w,
                        __bf16* __restrict__ xt, __bf16* __restrict__ wfrag) {
    const int bid = blockIdx.x, t = threadIdx.x;
    __shared__ __bf16 sw[16 * SWPAD];
    if (bid < 4096) {
        const int c8q = bid & 7, hwt = (bid >> 3) & 63, b = bid >> 9;
        const int hw = hwt * 64 + (t & 63);
        const int c8 = c8q * 4 + (t >> 6);
        const float* xp = x + ((size_t)(b * CIN + c8 * 8) << 12) + hw;
        bf16x8 v;
#pragma unroll
        for (int j = 0; j < 8; j++) v[j] = (__bf16)xp[(size_t)j << 12];
        *(bf16x8*)&xt[(((size_t)b << 12) + hw) * 256 + c8 * 8] = v;
    } else {
        const int mt = (bid - 4096) >> 1, gh = (bid - 4096) & 1;
        const int o0 = mt * 16, g0 = gh * 2;
        const int r = t >> 4, tr = t & 15;
        const float* wp = w + (size_t)(o0 + r) * (CIN * Kn) + g0 * (CPG * Kn);
#pragma unroll
        for (int it = 0; it < 18; it++) {
            int off = it * 64 + tr * 4;
            float4 v = *(const float4*)(wp + off);
            __bf16* d = &sw[r * SWPAD + off];
            d[0] = (__bf16)v.x; d[1] = (__bf16)v.y;
            d[2] = (__bf16)v.z; d[3] = (__bf16)v.w;
        }
        __syncthreads();
#pragma unroll
        for (int it = 0; it < 9; it++) {
            int chunk = it * 256 + t;
            int lane = chunk & 63, ks = (chunk >> 6) & 1, gkl = chunk >> 7;
            int gl = gkl / Kn, k = gkl - gl * Kn;
            int gk = g0 * Kn + gkl;
            int ol = lane & 15;
            int cbase = ks * 32 + (lane >> 4) * 8;
            bf16x8 v;
#pragma unroll
            for (int j = 0; j < 8; j++)
                v[j] = sw[ol * SWPAD + (gl * CPG + cbase + j) * Kn + k];
            *(bf16x8*)&wfrag[(((size_t)gk * 16 + mt) * 2 + ks) * 512 + lane * 8] = v;
        }
    }
}

// ---------------------------------------------------------------------------
// Main: 512 blocks x 512 threads. Block = bp*128 + h*2 + wh.
// N = 64 (2 b x 32 w); M = 256 over 8 waves (32 o-rows each). K = 36*64.
// ---------------------------------------------------------------------------
__global__ __launch_bounds__(512, 4)
void fa_main(const __bf16* __restrict__ xt, const float* __restrict__ shp,
             const float* __restrict__ w_off, const __bf16* __restrict__ wfrag,
             float* __restrict__ out) {
    const int blk = blockIdx.x;
    const int bp = blk >> 7, h = (blk >> 1) & 63, wh = blk & 1;
    const int w0 = wh * 32;
    const int t = threadIdx.x;
    const int wid = t >> 6, lane = t & 63;      // wid in [0,8): m-stripe 32
    const int col = lane & 15, quad = lane >> 4;
    const int cg = t & 7, nl = (t >> 3) & 63;   // staging: 1 task = (cg, nl)

    __shared__ int   s_iyx[GK * 64];
    __shared__ float s_fy[GK * 64];
    __shared__ float s_fx[GK * 64];
    __shared__ __align__(16) __bf16 sB[2][64 * 64];   // [n][c] xor-swizzled

    // ---- meta: (gk, n) ----
    for (int i = t; i < GK * 64; i += 512) {
        int gk = i >> 6, n = i & 63;
        int bb = n >> 5, w = w0 + (n & 31);
        int b = bp * 2 + bb;
        int g = gk / Kn, k = gk - g * Kn;
        int ky = k / 3, kx = k - ky * 3;
        int oy = (g * Kn + k) * 2;
        float dy = 0.f, dx = 0.f;
#pragma unroll
        for (int c = 0; c < 4; c++) {
            float sv = shp[((b * 4 + c) * Hn + h) * Wn + w];
            dy = fmaf(w_off[(oy    ) * 4 + c], sv, dy);
            dx = fmaf(w_off[(oy + 1) * 4 + c], sv, dx);
        }
        float py = (float)(h + ky - 1) + dy;
        float px = (float)(w + kx - 1) + dx;
        float y0 = floorf(py), x0 = floorf(px);
        s_fy[i] = py - y0;
        s_fx[i] = px - x0;
        s_iyx[i] = (((int)y0 & 0xffff) << 16) | ((int)x0 & 0xffff);
    }

    bf16x8 c4[4];
    float  w4[4];

    auto issue = [&](int gk) {
        int b = bp * 2 + (nl >> 5);
        int m = gk * 64 + nl;
        int g = gk / Kn;
        int pk = s_iyx[m];
        int iy = pk >> 16, ix = (pk << 16) >> 16;
        float fy = s_fy[m], fx = s_fx[m];
        bool y0v = (unsigned)iy       < (unsigned)Hn;
        bool y1v = (unsigned)(iy + 1) < (unsigned)Hn;
        bool x0v = (unsigned)ix       < (unsigned)Wn;
        bool x1v = (unsigned)(ix + 1) < (unsigned)Wn;
        int yc0 = min(max(iy, 0), Hn - 1), yc1 = min(max(iy + 1, 0), Hn - 1);
        int xc0 = min(max(ix, 0), Wn - 1), xc1 = min(max(ix + 1, 0), Wn - 1);
        const __bf16* base = xt + (((size_t)b << 12)) * 256 + g * CPG + cg * 8;
        c4[0] = *(const bf16x8*)(base + ((size_t)(yc0 * 64 + xc0)) * 256);
        c4[1] = *(const bf16x8*)(base + ((size_t)(yc0 * 64 + xc1)) * 256);
        c4[2] = *(const bf16x8*)(base + ((size_t)(yc1 * 64 + xc0)) * 256);
        c4[3] = *(const bf16x8*)(base + ((size_t)(yc1 * 64 + xc1)) * 256);
        float wy1 = fy, wy0 = 1.f - fy, wx1 = fx, wx0 = 1.f - fx;
        w4[0] = (y0v && x0v) ? wy0 * wx0 : 0.f;
        w4[1] = (y0v && x1v) ? wy0 * wx1 : 0.f;
        w4[2] = (y1v && x0v) ? wy1 * wx0 : 0.f;
        w4[3] = (y1v && x1v) ? wy1 * wx1 : 0.f;
    };
    auto commit = [&](int buf) {
        bf16x8 r;
#pragma unroll
        for (int j = 0; j < 8; j++) {
            float v = w4[0] * (float)c4[0][j] + w4[1] * (float)c4[1][j]
                    + w4[2] * (float)c4[2][j] + w4[3] * (float)c4[3][j];
            r[j] = (__bf16)v;
        }
        *(bf16x8*)&sB[buf][(nl * 8 + (cg ^ (nl & 7))) * 8] = r;
    };

    f32x4 acc[2][4];
#pragma unroll
    for (int mt = 0; mt < 2; mt++)
#pragma unroll
        for (int nt = 0; nt < 4; nt++) acc[mt][nt] = (f32x4){0.f, 0.f, 0.f, 0.f};

    __syncthreads();            // meta visible

    issue(0);
    commit(0);                  // sB[0] = tile 0
    issue(1);                   // corners(1) in regs
    __syncthreads();

    for (int gk = 0; gk < GK; gk++) {
        const int buf = gk & 1;
        // 1) A-frags for THIS gk (oldest vm loads; corner loads below stay
        //    in flight across the MFMA's wait)
        const __bf16* wbase = wfrag + (((size_t)gk * 16 + wid * 2) * 2) * 512;
        bf16x8 af[2][2];
#pragma unroll
        for (int ks = 0; ks < 2; ks++)
#pragma unroll
            for (int mt = 0; mt < 2; mt++)
                af[ks][mt] = *(const bf16x8*)(wbase + ((size_t)(mt * 2 + ks) * 64 + lane) * 8);
        // 2) interp gk+1 (corners landed last iter) -> other buffer
        if (gk + 1 < GK) commit(buf ^ 1);
        // 3) corner loads for gk+2
        if (gk + 2 < GK) issue(gk + 2);
        // 4) MFMA on buf
#pragma unroll
        for (int ks = 0; ks < 2; ks++) {
            bf16x8 bfv[4];
#pragma unroll
            for (int nt = 0; nt < 4; nt++) {
                int n = nt * 16 + col;
                int cq8 = ks * 4 + quad;
                bfv[nt] = *(const bf16x8*)&sB[buf][(n * 8 + (cq8 ^ (n & 7))) * 8];
            }
#pragma unroll
            for (int mt = 0; mt < 2; mt++)
#pragma unroll
                for (int nt = 0; nt < 4; nt++)
                    acc[mt][nt] = __builtin_amdgcn_mfma_f32_16x16x32_bf16(
                        af[ks][mt], bfv[nt], acc[mt][nt], 0, 0, 0);
        }
        __syncthreads();
    }

    // ---- epilogue: o = wid*32 + mt*16 + quad*4 + r ; n = nt*16 + col ----
#pragma unroll
    for (int mt = 0; mt < 2; mt++)
#pragma unroll
        for (int r = 0; r < 4; r++) {
            int o = wid * 32 + mt * 16 + quad * 4 + r;
#pragma unroll
            for (int nt = 0; nt < 4; nt++) {
                int n = nt * 16 + col;
                int b = bp * 2 + (n >> 5);
                int w = w0 + (n & 31);
                out[(((size_t)(b * COUT + o)) << 12) + h * Wn + w] =
                    fmaxf(acc[mt][nt][r], 0.f);
            }
        }
}

// ---------------------------------------------------------------------------
extern "C" void kernel_launch(void* const* d_in, const int* in_sizes, int n_in,
                              void* d_out, int out_size, void* d_ws, size_t ws_size,
                              hipStream_t stream) {
    const float* x     = (const float*)d_in[0];
    const float* shp   = (const float*)d_in[1];
    const float* w_off = (const float*)d_in[2];
    const float* w_def = (const float*)d_in[3];
    float* out = (float*)d_out;
    __bf16* wfrag = (__bf16*)d_ws;                         // 1.18 MB
    __bf16* xt    = (__bf16*)((char*)d_ws + (2u << 20));   // 16.8 MB

    fa_prep<<<4096 + 32, 256, 0, stream>>>(x, w_def, xt, wfrag);
    fa_main<<<512, 512, 0, stream>>>(xt, shp, w_off, wfrag, out);
}

// Round 8
// 146.363 us; speedup vs baseline: 4.9923x; 1.0073x over previous
//
#include <hip/hip_runtime.h>
#include <hip/hip_bf16.h>

// FeatureAlign deformable 3x3 conv, G=4, PAD=1.
// R8 = R7 (per-(gk,n) sampling math hoisted to 16B LDS meta records) with the
// s_woff staging bug fixed: R7 only wrote 256 of 288 w_off floats (gk 32..35
// sampled garbage -> absmax 0.54). Now a grid-stride loop covers all 288.
// issue() = 1 ds_read_b128 + 4 addr + 4 b128 gathers; commit() = interp only.
// Grid/pipeline unchanged from R6 (512 blk x 512 thr, 2 blocks/CU).

#define Bn   8
#define CIN  256
#define COUT 256
#define Hn   64
#define Wn   64
#define Gn   4
#define Kn   9
#define CPG  64
#define GK   36

typedef __bf16 bf16x8 __attribute__((ext_vector_type(8)));
typedef float  f32x4  __attribute__((ext_vector_type(4)));
typedef _Float16 f16x2 __attribute__((ext_vector_type(2)));

// ---------------------------------------------------------------------------
// Fused prep (unchanged from R5/R6).
//  blocks [0, 4096):        x (b,c,y,x) f32 -> xt (b, y*64+x, c) bf16 [NHWC]
//  blocks [4096, 4096+32):  w_deform -> fragment-linear bf16 wfrag
// ---------------------------------------------------------------------------
#define SWPAD 1156
__global__ void fa_prep(const float* __restrict__ x, const float* __restrict__ w,
                        __bf16* __restrict__ xt, __bf16* __restrict__ wfrag) {
    const int bid = blockIdx.x, t = threadIdx.x;
    __shared__ __bf16 sw[16 * SWPAD];
    if (bid < 4096) {
        const int c8q = bid & 7, hwt = (bid >> 3) & 63, b = bid >> 9;
        const int hw = hwt * 64 + (t & 63);
        const int c8 = c8q * 4 + (t >> 6);
        const float* xp = x + ((size_t)(b * CIN + c8 * 8) << 12) + hw;
        bf16x8 v;
#pragma unroll
        for (int j = 0; j < 8; j++) v[j] = (__bf16)xp[(size_t)j << 12];
        *(bf16x8*)&xt[(((size_t)b << 12) + hw) * 256 + c8 * 8] = v;
    } else {
        const int mt = (bid - 4096) >> 1, gh = (bid - 4096) & 1;
        const int o0 = mt * 16, g0 = gh * 2;
        const int r = t >> 4, tr = t & 15;
        const float* wp = w + (size_t)(o0 + r) * (CIN * Kn) + g0 * (CPG * Kn);
#pragma unroll
        for (int it = 0; it < 18; it++) {
            int off = it * 64 + tr * 4;
            float4 v = *(const float4*)(wp + off);
            __bf16* d = &sw[r * SWPAD + off];
            d[0] = (__bf16)v.x; d[1] = (__bf16)v.y;
            d[2] = (__bf16)v.z; d[3] = (__bf16)v.w;
        }
        __syncthreads();
#pragma unroll
        for (int it = 0; it < 9; it++) {
            int chunk = it * 256 + t;
            int lane = chunk & 63, ks = (chunk >> 6) & 1, gkl = chunk >> 7;
            int gl = gkl / Kn, k = gkl - gl * Kn;
            int gk = g0 * Kn + gkl;
            int ol = lane & 15;
            int cbase = ks * 32 + (lane >> 4) * 8;
            bf16x8 v;
#pragma unroll
            for (int j = 0; j < 8; j++)
                v[j] = sw[ol * SWPAD + (gl * CPG + cbase + j) * Kn + k];
            *(bf16x8*)&wfrag[(((size_t)gk * 16 + mt) * 2 + ks) * 512 + lane * 8] = v;
        }
    }
}

// ---------------------------------------------------------------------------
// Main: 512 blocks x 512 threads. Block = bp*128 + h*2 + wh.
// N = 64 (2 b x 32 w); M = 256 over 8 waves (32 o-rows each). K = 36*64.
// ---------------------------------------------------------------------------
__global__ __launch_bounds__(512, 4)
void fa_main(const __bf16* __restrict__ xt, const float* __restrict__ shp,
             const float* __restrict__ w_off, const __bf16* __restrict__ wfrag,
             float* __restrict__ out) {
    const int blk = blockIdx.x;
    const int bp = blk >> 7, h = (blk >> 1) & 63, wh = blk & 1;
    const int w0 = wh * 32;
    const int t = threadIdx.x;
    const int wid = t >> 6, lane = t & 63;
    const int col = lane & 15, quad = lane >> 4;
    const int cg = t & 7, nl = (t >> 3) & 63;

    __shared__ __align__(16) int4 s_meta[GK * 64];        // 36864 B
    __shared__ __align__(16) __bf16 sB[2][64 * 64];       // 16384 B
    __shared__ float s_shp[2 * 4 * 32];                   // 1024 B
    __shared__ float s_woff[GK * 8];                      // 1152 B

    // ---- stage shp slice (2 b x 4 c x 32 w at row h) + ALL 288 w_off ----
    if (t < 256) {
        int bb = t >> 7, c = (t >> 5) & 3, wl = t & 31;
        s_shp[t] = shp[(((bp * 2 + bb) * 4 + c) << 12) + h * Wn + w0 + wl];
    }
    for (int u = t; u < GK * 8; u += 512) s_woff[u] = w_off[u];
    __syncthreads();

    // ---- meta: one 16B record per (gk, n) ----
    for (int i = t; i < GK * 64; i += 512) {
        int gk = i >> 6, n = i & 63;
        int bb = n >> 5, wl = n & 31;
        int g = gk / Kn, k = gk - g * Kn;
        int ky = k / 3, kx = k - ky * 3;
        float dy = 0.f, dx = 0.f;
#pragma unroll
        for (int c = 0; c < 4; c++) {
            float sv = s_shp[(bb * 4 + c) * 32 + wl];
            dy = fmaf(s_woff[gk * 8 + c],     sv, dy);
            dx = fmaf(s_woff[gk * 8 + 4 + c], sv, dx);
        }
        float py = (float)(h + ky - 1) + dy;
        float px = (float)(w0 + wl + kx - 1) + dx;
        float y0 = floorf(py), x0 = floorf(px);
        float fy = py - y0, fx = px - x0;
        int iy = (int)y0, ix = (int)x0;
        bool y0v = (unsigned)iy       < (unsigned)Hn;
        bool y1v = (unsigned)(iy + 1) < (unsigned)Hn;
        bool x0v = (unsigned)ix       < (unsigned)Wn;
        bool x1v = (unsigned)(ix + 1) < (unsigned)Wn;
        int yc0 = min(max(iy, 0), Hn - 1), yc1 = min(max(iy + 1, 0), Hn - 1);
        int xc0 = min(max(ix, 0), Wn - 1), xc1 = min(max(ix + 1, 0), Wn - 1);
        int l00 = yc0 * Wn + xc0, l01 = yc0 * Wn + xc1;
        int l10 = yc1 * Wn + xc0, l11 = yc1 * Wn + xc1;
        float wy1 = fy, wy0 = 1.f - fy, wx1 = fx, wx0 = 1.f - fx;
        float w00 = (y0v && x0v) ? wy0 * wx0 : 0.f;
        float w01 = (y0v && x1v) ? wy0 * wx1 : 0.f;
        float w10 = (y1v && x0v) ? wy1 * wx0 : 0.f;
        float w11 = (y1v && x1v) ? wy1 * wx1 : 0.f;
        f16x2 p0, p1;
        p0.x = (_Float16)w00; p0.y = (_Float16)w01;
        p1.x = (_Float16)w10; p1.y = (_Float16)w11;
        s_meta[i] = make_int4(l00 | (l01 << 16), l10 | (l11 << 16),
                              __builtin_bit_cast(int, p0),
                              __builtin_bit_cast(int, p1));
    }

    bf16x8 c4[4];
    int2   amv;

    auto issue = [&](int gk) {
        int4 mv = s_meta[gk * 64 + nl];
        amv.x = mv.z; amv.y = mv.w;
        int b = bp * 2 + (nl >> 5);
        int g = gk / Kn;
        const __bf16* base = xt + (((size_t)b << 12)) * 256 + g * CPG + cg * 8;
        c4[0] = *(const bf16x8*)(base + (size_t)(mv.x & 0xffff) * 256);
        c4[1] = *(const bf16x8*)(base + (size_t)((unsigned)mv.x >> 16) * 256);
        c4[2] = *(const bf16x8*)(base + (size_t)(mv.y & 0xffff) * 256);
        c4[3] = *(const bf16x8*)(base + (size_t)((unsigned)mv.y >> 16) * 256);
    };
    auto commit = [&](int buf) {
        f16x2 h0 = __builtin_bit_cast(f16x2, amv.x);
        f16x2 h1 = __builtin_bit_cast(f16x2, amv.y);
        float w00 = (float)h0.x, w01 = (float)h0.y;
        float w10 = (float)h1.x, w11 = (float)h1.y;
        bf16x8 r;
#pragma unroll
        for (int j = 0; j < 8; j++) {
            float v = w00 * (float)c4[0][j] + w01 * (float)c4[1][j]
                    + w10 * (float)c4[2][j] + w11 * (float)c4[3][j];
            r[j] = (__bf16)v;
        }
        *(bf16x8*)&sB[buf][(nl * 8 + (cg ^ (nl & 7))) * 8] = r;
    };

    f32x4 acc[2][4];
#pragma unroll
    for (int mt = 0; mt < 2; mt++)
#pragma unroll
        for (int nt = 0; nt < 4; nt++) acc[mt][nt] = (f32x4){0.f, 0.f, 0.f, 0.f};

    __syncthreads();            // meta visible

    issue(0);
    commit(0);                  // sB[0] = tile 0
    issue(1);                   // corners(1) in regs
    __syncthreads();

    for (int gk = 0; gk < GK; gk++) {
        const int buf = gk & 1;
        // 1) A-frags for THIS gk (oldest vm loads; corner loads stay in
        //    flight across the MFMA's wait)
        const __bf16* wbase = wfrag + (((size_t)gk * 16 + wid * 2) * 2) * 512;
        bf16x8 af[2][2];
#pragma unroll
        for (int ks = 0; ks < 2; ks++)
#pragma unroll
            for (int mt = 0; mt < 2; mt++)
                af[ks][mt] = *(const bf16x8*)(wbase + ((size_t)(mt * 2 + ks) * 64 + lane) * 8);
        // 2) interp gk+1 (corners landed last iter) -> other buffer
        if (gk + 1 < GK) commit(buf ^ 1);
        // 3) corner loads for gk+2
        if (gk + 2 < GK) issue(gk + 2);
        // 4) MFMA on buf
#pragma unroll
        for (int ks = 0; ks < 2; ks++) {
            bf16x8 bfv[4];
#pragma unroll
            for (int nt = 0; nt < 4; nt++) {
                int n = nt * 16 + col;
                int cq8 = ks * 4 + quad;
                bfv[nt] = *(const bf16x8*)&sB[buf][(n * 8 + (cq8 ^ (n & 7))) * 8];
            }
#pragma unroll
            for (int mt = 0; mt < 2; mt++)
#pragma unroll
                for (int nt = 0; nt < 4; nt++)
                    acc[mt][nt] = __builtin_amdgcn_mfma_f32_16x16x32_bf16(
                        af[ks][mt], bfv[nt], acc[mt][nt], 0, 0, 0);
        }
        __syncthreads();
    }

    // ---- epilogue: o = wid*32 + mt*16 + quad*4 + r ; n = nt*16 + col ----
#pragma unroll
    for (int mt = 0; mt < 2; mt++)
#pragma unroll
        for (int r = 0; r < 4; r++) {
            int o = wid * 32 + mt * 16 + quad * 4 + r;
#pragma unroll
            for (int nt = 0; nt < 4; nt++) {
                int n = nt * 16 + col;
                int b = bp * 2 + (n >> 5);
                int w = w0 + (n & 31);
                out[(((size_t)(b * COUT + o)) << 12) + h * Wn + w] =
                    fmaxf(acc[mt][nt][r], 0.f);
            }
        }
}

// ---------------------------------------------------------------------------
extern "C" void kernel_launch(void* const* d_in, const int* in_sizes, int n_in,
                              void* d_out, int out_size, void* d_ws, size_t ws_size,
                              hipStream_t stream) {
    const float* x     = (const float*)d_in[0];
    const float* shp   = (const float*)d_in[1];
    const float* w_off = (const float*)d_in[2];
    const float* w_def = (const float*)d_in[3];
    float* out = (float*)d_out;
    __bf16* wfrag = (__bf16*)d_ws;                         // 1.18 MB
    __bf16* xt    = (__bf16*)((char*)d_ws + (2u << 20));   // 16.8 MB

    fa_prep<<<4096 + 32, 256, 0, stream>>>(x, w_def, xt, wfrag);
    fa_main<<<512, 512, 0, stream>>>(xt, shp, w_off, wfrag, out);
}